// Round 10
// baseline (499.761 us; speedup 1.0000x reference)
//
#include <hip/hip_runtime.h>
#include <hip/hip_bf16.h>
#include <math.h>

typedef _Float16 half8  __attribute__((ext_vector_type(8)));
typedef __fp16   fp16x2 __attribute__((ext_vector_type(2)));
typedef float    floatx4 __attribute__((ext_vector_type(4)));

#define IN_CH 64
#define HID   128
#define NSEG  4096
// MEASUREMENT ROUND: repeat the (idempotent) MLP tile loop 4x inside ONE
// dispatch so mlp_score exceeds the ~320us poison fills and appears in the
// top-5 rocprof rows with full counters. T_mlp = dispatch/4, and
// T_mlp = (dur_us - 196.6)/3 as cross-check.
#define MLP_REPS 4

__device__ __forceinline__ unsigned fkey(float s) {
    unsigned u = __float_as_uint(s);
    return (u & 0x80000000u) ? ~u : (u | 0x80000000u);
}
__device__ __forceinline__ float funkey(unsigned k) {
    unsigned u = (k & 0x80000000u) ? (k ^ 0x80000000u) : ~k;
    return __uint_as_float(u);
}

// ---------------- init segment scratch ----------------
__global__ void init_seg(unsigned* __restrict__ segkey, float* __restrict__ denom) {
    int i = blockIdx.x * blockDim.x + threadIdx.x;
    if (i < NSEG) { segkey[i] = 0u; denom[i] = 0.0f; }
}

// ---------------- fused MLP -> scores ----------------
// R9 structure unchanged (swapped-operand MFMA, per-wave depth-4 LDS ring,
// contiguous 1KB global_load_lds with source-side XOR swizzle, counted vmcnt),
// wrapped in a 4x repeat loop for profiling visibility.
__global__ __launch_bounds__(256, 2) void mlp_score(
    const float* __restrict__ x, const float* __restrict__ w1,
    const float* __restrict__ b1, const float* __restrict__ w2,
    const float* __restrict__ b2, float* __restrict__ score, int E)
{
    __shared__ __align__(16) char smem[4 * 4 * 4096];   // 64 KB

    const int tid  = threadIdx.x;
    const int lane = tid & 63;
    const int wid  = tid >> 6;
    const int g    = lane >> 4;   // 0..3
    const int l15  = lane & 15;   // 0..15
    const int ls4  = lane >> 4;

    // ---- one-time: w1 A-fragments (64 VGPRs), RTN cvt
    half8 afr[2][8];
#pragma unroll
    for (int ks = 0; ks < 2; ++ks)
#pragma unroll
        for (int ct = 0; ct < 8; ++ct) {
            const float* wp = w1 + (size_t)(ks * 32 + g * 8) * HID + ct * 16 + l15;
            half8 h;
#pragma unroll
            for (int j = 0; j < 8; ++j) h[j] = (_Float16)wp[(size_t)j * HID];
            afr[ks][ct] = h;
        }

    // ---- one-time: bias-as-C and w2 fragments
    floatx4 biasC[8], w2r[8];
#pragma unroll
    for (int ct = 0; ct < 8; ++ct)
#pragma unroll
        for (int r = 0; r < 4; ++r) {
            biasC[ct][r] = b1[ct * 16 + g * 4 + r];
            w2r[ct][r]   = w2[ct * 16 + g * 4 + r];
        }
    const float b2v = b2[0];

    const int nwtile = E >> 4;                  // 16-edge tiles
    const int TOTW   = (int)gridDim.x * 4;      // total waves
    const int gw     = blockIdx.x * 4 + wid;
    const int n      = nwtile / TOTW;           // tiles per wave
    const int rem    = nwtile - n * TOTW;

    char* lwave = smem + wid * 16384;
    const char* xb = (const char*)x;

    // writer per-lane global offsets (within tile), one per 1KB chunk:
    // chunk c, lane(ls4,l15) -> row r=c*4+ls4; LDS slot u=l15 gets G[r][u^r].
    unsigned woff[4];
#pragma unroll
    for (int c = 0; c < 4; ++c) {
        int r = c * 4 + ls4;
        woff[c] = (unsigned)(r * 256 + ((l15 ^ r) & 15) * 16);
    }
    // reader: G[l15][unit v] lives at slot v^l15 of LDS row l15
    const unsigned roff = (unsigned)(l15 * 256 + (((2 * g) ^ l15) & 15) * 16);

    union H8 { half8 h8; fp16x2 h2[4]; };

#define STAGE(I) do {                                                          \
        size_t tb_ = (size_t)(gw + (I) * TOTW) * 4096;                         \
        char* lb_ = lwave + ((I) & 3) * 4096;                                  \
        __builtin_amdgcn_global_load_lds((const __attribute__((address_space(1))) void*)(xb + tb_ + woff[0]), (__attribute__((address_space(3))) void*)(lb_),        16, 0, 0); \
        __builtin_amdgcn_global_load_lds((const __attribute__((address_space(1))) void*)(xb + tb_ + woff[1]), (__attribute__((address_space(3))) void*)(lb_ + 1024), 16, 0, 0); \
        __builtin_amdgcn_global_load_lds((const __attribute__((address_space(1))) void*)(xb + tb_ + woff[2]), (__attribute__((address_space(3))) void*)(lb_ + 2048), 16, 0, 0); \
        __builtin_amdgcn_global_load_lds((const __attribute__((address_space(1))) void*)(xb + tb_ + woff[3]), (__attribute__((address_space(3))) void*)(lb_ + 3072), 16, 0, 0); \
    } while (0)

#define CORE(F0, F1, F2, F3, WT) do {                                          \
        H8 ub, uc;                                                             \
        ub.h2[0] = __builtin_amdgcn_cvt_pkrtz(F0[0], F0[1]);                   \
        ub.h2[1] = __builtin_amdgcn_cvt_pkrtz(F0[2], F0[3]);                   \
        ub.h2[2] = __builtin_amdgcn_cvt_pkrtz(F1[0], F1[1]);                   \
        ub.h2[3] = __builtin_amdgcn_cvt_pkrtz(F1[2], F1[3]);                   \
        uc.h2[0] = __builtin_amdgcn_cvt_pkrtz(F2[0], F2[1]);                   \
        uc.h2[1] = __builtin_amdgcn_cvt_pkrtz(F2[2], F2[3]);                   \
        uc.h2[2] = __builtin_amdgcn_cvt_pkrtz(F3[0], F3[1]);                   \
        uc.h2[3] = __builtin_amdgcn_cvt_pkrtz(F3[2], F3[3]);                   \
        floatx4 acc[8];                                                        \
        _Pragma("unroll")                                                      \
        for (int ct = 0; ct < 8; ++ct)                                         \
            acc[ct] = __builtin_amdgcn_mfma_f32_16x16x32_f16(afr[0][ct], ub.h8, biasC[ct], 0, 0, 0); \
        _Pragma("unroll")                                                      \
        for (int ct = 0; ct < 8; ++ct)                                         \
            acc[ct] = __builtin_amdgcn_mfma_f32_16x16x32_f16(afr[1][ct], uc.h8, acc[ct], 0, 0, 0);   \
        float s0 = 0.f, s1 = 0.f, s2 = 0.f, s3 = 0.f;                          \
        _Pragma("unroll")                                                      \
        for (int ct = 0; ct < 8; ++ct) {                                       \
            s0 += fmaxf(acc[ct][0], 0.f) * w2r[ct][0];                         \
            s1 += fmaxf(acc[ct][1], 0.f) * w2r[ct][1];                         \
            s2 += fmaxf(acc[ct][2], 0.f) * w2r[ct][2];                         \
            s3 += fmaxf(acc[ct][3], 0.f) * w2r[ct][3];                         \
        }                                                                      \
        float s = (s0 + s1) + (s2 + s3);                                       \
        s += __shfl_xor(s, 16);                                                \
        s += __shfl_xor(s, 32);                                                \
        if (lane < 16)                                                         \
            score[(size_t)(WT) * 16 + l15] = s + b2v;                          \
    } while (0)

#define BODY(I) do {                                                           \
        const char* lb_ = lwave + ((I) & 3) * 4096;                            \
        floatx4 f0 = *(const floatx4*)(lb_ + roff);                            \
        floatx4 f1 = *(const floatx4*)(lb_ + (roff ^ 16u));                    \
        floatx4 f2 = *(const floatx4*)(lb_ + (roff ^ 128u));                   \
        floatx4 f3 = *(const floatx4*)(lb_ + (roff ^ 144u));                   \
        CORE(f0, f1, f2, f3, gw + (I) * TOTW);                                 \
        __builtin_amdgcn_sched_barrier(0);                                     \
    } while (0)

    for (int rep = 0; rep < MLP_REPS; ++rep) {
        if (n >= 4) {
            STAGE(0); STAGE(1); STAGE(2);
            int i = 0;
            for (; i < n - 3; ++i) {
                STAGE(i + 3);
                asm volatile("s_waitcnt vmcnt(12)" ::: "memory");
                __builtin_amdgcn_sched_barrier(0);
                BODY(i);
            }
            asm volatile("s_waitcnt vmcnt(8)" ::: "memory");
            __builtin_amdgcn_sched_barrier(0);
            BODY(i); ++i;
            asm volatile("s_waitcnt vmcnt(4)" ::: "memory");
            __builtin_amdgcn_sched_barrier(0);
            BODY(i); ++i;
            asm volatile("s_waitcnt vmcnt(0)" ::: "memory");
            __builtin_amdgcn_sched_barrier(0);
            BODY(i);
        } else {
            for (int i = 0; i < n; ++i) {
                const float* xr = x + (size_t)(gw + i * TOTW) * (16 * IN_CH)
                                    + (size_t)l15 * IN_CH + g * 8;
                floatx4 f0 = *(const floatx4*)(xr);
                floatx4 f1 = *(const floatx4*)(xr + 4);
                floatx4 f2 = *(const floatx4*)(xr + 32);
                floatx4 f3 = *(const floatx4*)(xr + 36);
                CORE(f0, f1, f2, f3, gw + i * TOTW);
            }
        }
        if (gw < rem) {   // remainder tiles (0 for E = 2^21)
            int wt_ = n * TOTW + gw;
            const float* xr = x + (size_t)wt_ * (16 * IN_CH) + (size_t)l15 * IN_CH + g * 8;
            floatx4 f0 = *(const floatx4*)(xr);
            floatx4 f1 = *(const floatx4*)(xr + 4);
            floatx4 f2 = *(const floatx4*)(xr + 32);
            floatx4 f3 = *(const floatx4*)(xr + 36);
            CORE(f0, f1, f2, f3, wt_);
        }
    }
#undef STAGE
#undef CORE
#undef BODY
}

// ---------------- segment max (run-compressed atomics) ----------------
__global__ __launch_bounds__(256) void seg_max(
    const float* __restrict__ score, const int* __restrict__ batch,
    unsigned* __restrict__ segkey, int E)
{
    int t = blockIdx.x * 256 + threadIdx.x;
    int i0 = t * 8;
    if (i0 + 8 > E) return;
    int4 bA = *(const int4*)(batch + i0);
    int4 bB = *(const int4*)(batch + i0 + 4);
    floatx4 sA = *(const floatx4*)(score + i0);
    floatx4 sB = *(const floatx4*)(score + i0 + 4);
    int   ids[8] = {bA.x, bA.y, bA.z, bA.w, bB.x, bB.y, bB.z, bB.w};
    float ss[8]  = {sA[0], sA[1], sA[2], sA[3], sB[0], sB[1], sB[2], sB[3]};
    int cur = ids[0];
    float m = ss[0];
#pragma unroll
    for (int j = 1; j < 8; ++j) {
        if (ids[j] == cur) {
            m = fmaxf(m, ss[j]);
        } else {
            atomicMax(segkey + cur, fkey(m));
            cur = ids[j];
            m = ss[j];
        }
    }
    atomicMax(segkey + cur, fkey(m));
}

// ---------------- segment denom (run-compressed atomics) ----------------
__global__ __launch_bounds__(256) void seg_denom(
    const float* __restrict__ score, const int* __restrict__ batch,
    const unsigned* __restrict__ segkey, float* __restrict__ denom, int E)
{
    int t = blockIdx.x * 256 + threadIdx.x;
    int i0 = t * 8;
    if (i0 + 8 > E) return;
    int4 bA = *(const int4*)(batch + i0);
    int4 bB = *(const int4*)(batch + i0 + 4);
    floatx4 sA = *(const floatx4*)(score + i0);
    floatx4 sB = *(const floatx4*)(score + i0 + 4);
    int   ids[8] = {bA.x, bA.y, bA.z, bA.w, bB.x, bB.y, bB.z, bB.w};
    float ss[8]  = {sA[0], sA[1], sA[2], sA[3], sB[0], sB[1], sB[2], sB[3]};
    int cur = ids[0];
    float m = funkey(segkey[cur]);
    float a = __expf(ss[0] - m);
#pragma unroll
    for (int j = 1; j < 8; ++j) {
        if (ids[j] == cur) {
            a += __expf(ss[j] - m);
        } else {
            atomicAdd(denom + cur, a);
            cur = ids[j];
            m = funkey(segkey[cur]);
            a = __expf(ss[j] - m);
        }
    }
    atomicAdd(denom + cur, a);
}

// ---------------- finalize: out = exp(s-m)/(denom+eps), in place ----------------
__global__ __launch_bounds__(256) void finalize(
    float* __restrict__ score, const int* __restrict__ batch,
    const unsigned* __restrict__ segkey, const float* __restrict__ denom, int E)
{
    int t = blockIdx.x * 256 + threadIdx.x;
    int i0 = t * 8;
    if (i0 + 8 > E) return;
    int4 bA = *(const int4*)(batch + i0);
    int4 bB = *(const int4*)(batch + i0 + 4);
    floatx4 sA = *(const floatx4*)(score + i0);
    floatx4 sB = *(const floatx4*)(score + i0 + 4);
    int   ids[8] = {bA.x, bA.y, bA.z, bA.w, bB.x, bB.y, bB.z, bB.w};
    float ss[8]  = {sA[0], sA[1], sA[2], sA[3], sB[0], sB[1], sB[2], sB[3]};
    floatx4 oA, oB;
#pragma unroll
    for (int j = 0; j < 4; ++j) {
        float mj = funkey(segkey[ids[j]]);
        oA[j] = __expf(ss[j] - mj) / (denom[ids[j]] + 1e-16f);
    }
#pragma unroll
    for (int j = 0; j < 4; ++j) {
        float mj = funkey(segkey[ids[j + 4]]);
        oB[j] = __expf(ss[j + 4] - mj) / (denom[ids[j + 4]] + 1e-16f);
    }
    *(floatx4*)(score + i0)     = oA;
    *(floatx4*)(score + i0 + 4) = oB;
}

extern "C" void kernel_launch(void* const* d_in, const int* in_sizes, int n_in,
                              void* d_out, int out_size, void* d_ws, size_t ws_size,
                              hipStream_t stream) {
    const float* x   = (const float*)d_in[0];
    const float* w1  = (const float*)d_in[1];
    const float* b1  = (const float*)d_in[2];
    const float* w2  = (const float*)d_in[3];
    const float* b2  = (const float*)d_in[4];
    const int* batch = (const int*)d_in[5];
    float* out = (float*)d_out;
    const int E = in_sizes[5];

    unsigned* segkey = (unsigned*)d_ws;
    float*    denom  = (float*)((char*)d_ws + NSEG * sizeof(unsigned));

    init_seg<<<(NSEG + 255) / 256, 256, 0, stream>>>(segkey, denom);
    // scores are written into d_out (reused as scratch), finalized in place
    mlp_score<<<512, 256, 0, stream>>>(x, w1, b1, w2, b2, out, E);
    const int nthr = E / 8;
    seg_max   <<<nthr / 256, 256, 0, stream>>>(out, batch, segkey, E);
    seg_denom <<<nthr / 256, 256, 0, stream>>>(out, batch, segkey, denom, E);
    finalize  <<<nthr / 256, 256, 0, stream>>>(out, batch, segkey, denom, E);
}

// Round 11
// 300.861 us; speedup vs baseline: 1.6611x; 1.6611x over previous
//
#include <hip/hip_runtime.h>
#include <hip/hip_bf16.h>
#include <math.h>

typedef _Float16 half8  __attribute__((ext_vector_type(8)));
typedef __fp16   fp16x2 __attribute__((ext_vector_type(2)));
typedef float    floatx4 __attribute__((ext_vector_type(4)));

#define IN_CH 64
#define HID   128
#define NSEG  4096

__device__ __forceinline__ unsigned fkey(float s) {
    unsigned u = __float_as_uint(s);
    return (u & 0x80000000u) ? ~u : (u | 0x80000000u);
}
__device__ __forceinline__ float funkey(unsigned k) {
    unsigned u = (k & 0x80000000u) ? (k ^ 0x80000000u) : ~k;
    return __uint_as_float(u);
}

// ---------------- init segment scratch ----------------
__global__ void init_seg(unsigned* __restrict__ segkey, float* __restrict__ denom) {
    int i = blockIdx.x * blockDim.x + threadIdx.x;
    if (i < NSEG) { segkey[i] = 0u; denom[i] = 0.0f; }
}

// ---------------- fused MLP -> scores ----------------
// R6-verified swapped-operand MFMA core. R11: NO LDS, NO global_load_lds --
// plain global_load_dwordx4 into registers (m13-proven 6.3TB/s path),
// depth-1 two-regset prefetch with asm-pinned issue, 12 waves/CU (grid 768,
// launch_bounds(256,3)). Diagnosis R10: latency-bound (VALU 30 / MFMA 12 /
// HBM 28 / Occ 21) -> raise TLP + use the ordinary VMEM path.
__global__ __launch_bounds__(256, 3) void mlp_score(
    const float* __restrict__ x, const float* __restrict__ w1,
    const float* __restrict__ b1, const float* __restrict__ w2,
    const float* __restrict__ b2, float* __restrict__ score, int E)
{
    const int tid  = threadIdx.x;
    const int lane = tid & 63;
    const int wid  = tid >> 6;
    const int g    = lane >> 4;   // 0..3
    const int l15  = lane & 15;   // 0..15

    // ---- one-time: w1 A-fragments (64 VGPRs), RTN cvt
    half8 afr[2][8];
#pragma unroll
    for (int ks = 0; ks < 2; ++ks)
#pragma unroll
        for (int ct = 0; ct < 8; ++ct) {
            const float* wp = w1 + (size_t)(ks * 32 + g * 8) * HID + ct * 16 + l15;
            half8 h;
#pragma unroll
            for (int j = 0; j < 8; ++j) h[j] = (_Float16)wp[(size_t)j * HID];
            afr[ks][ct] = h;
        }

    // ---- one-time: bias-as-C and w2 fragments
    floatx4 biasC[8], w2r[8];
#pragma unroll
    for (int ct = 0; ct < 8; ++ct)
#pragma unroll
        for (int r = 0; r < 4; ++r) {
            biasC[ct][r] = b1[ct * 16 + g * 4 + r];
            w2r[ct][r]   = w2[ct * 16 + g * 4 + r];
        }
    const float b2v = b2[0];

    const int nwtile = E >> 4;                  // 16-edge tiles
    const int TOTW   = (int)gridDim.x * 4;      // total waves
    const int gw     = blockIdx.x * 4 + wid;
    const int n      = nwtile / TOTW;           // tiles per wave
    const int rem    = nwtile - n * TOTW;
    const size_t laneoff = (size_t)l15 * IN_CH + g * 8;

    union H8 { half8 h8; fp16x2 h2[4]; };

#define TIDX(I) (gw + (I) * TOTW)

#define LOADSET(F, T) do {                                            \
        const float* xr = x + (size_t)(T) * (16 * IN_CH) + laneoff;   \
        F##0 = *(const floatx4*)(xr);                                 \
        F##1 = *(const floatx4*)(xr + 4);                             \
        F##2 = *(const floatx4*)(xr + 32);                            \
        F##3 = *(const floatx4*)(xr + 36);                            \
    } while (0)

#define CORE(F, WT) do {                                              \
        H8 ub, uc;                                                    \
        ub.h2[0] = __builtin_amdgcn_cvt_pkrtz(F##0[0], F##0[1]);      \
        ub.h2[1] = __builtin_amdgcn_cvt_pkrtz(F##0[2], F##0[3]);      \
        ub.h2[2] = __builtin_amdgcn_cvt_pkrtz(F##1[0], F##1[1]);      \
        ub.h2[3] = __builtin_amdgcn_cvt_pkrtz(F##1[2], F##1[3]);      \
        uc.h2[0] = __builtin_amdgcn_cvt_pkrtz(F##2[0], F##2[1]);      \
        uc.h2[1] = __builtin_amdgcn_cvt_pkrtz(F##2[2], F##2[3]);      \
        uc.h2[2] = __builtin_amdgcn_cvt_pkrtz(F##3[0], F##3[1]);      \
        uc.h2[3] = __builtin_amdgcn_cvt_pkrtz(F##3[2], F##3[3]);      \
        floatx4 acc[8];                                               \
        _Pragma("unroll")                                             \
        for (int ct = 0; ct < 8; ++ct)                                \
            acc[ct] = __builtin_amdgcn_mfma_f32_16x16x32_f16(afr[0][ct], ub.h8, biasC[ct], 0, 0, 0); \
        _Pragma("unroll")                                             \
        for (int ct = 0; ct < 8; ++ct)                                \
            acc[ct] = __builtin_amdgcn_mfma_f32_16x16x32_f16(afr[1][ct], uc.h8, acc[ct], 0, 0, 0);   \
        float s0 = 0.f, s1 = 0.f, s2 = 0.f, s3 = 0.f;                 \
        _Pragma("unroll")                                             \
        for (int ct = 0; ct < 8; ++ct) {                              \
            s0 += fmaxf(acc[ct][0], 0.f) * w2r[ct][0];                \
            s1 += fmaxf(acc[ct][1], 0.f) * w2r[ct][1];                \
            s2 += fmaxf(acc[ct][2], 0.f) * w2r[ct][2];                \
            s3 += fmaxf(acc[ct][3], 0.f) * w2r[ct][3];                \
        }                                                             \
        float s = (s0 + s1) + (s2 + s3);                              \
        s += __shfl_xor(s, 16);                                       \
        s += __shfl_xor(s, 32);                                       \
        if (lane < 16)                                                \
            score[(size_t)(WT) * 16 + l15] = s + b2v;                 \
    } while (0)

    // steady loop: two regsets A/B alternate; tile i+1 issued at top of the
    // iteration that consumes tile i. vmcnt(5) keeps [S(i-1), L(i+1)(4)]
    // outstanding while guaranteeing L(i) retired; compiler's own dependency
    // waits cover the tail cases.
    if (n > 0) {
        floatx4 A0, A1, A2, A3, B0, B1, B2, B3;
        LOADSET(A, TIDX(0));
        int i = 0;
        for (; i + 2 < n; i += 2) {
            LOADSET(B, TIDX(i + 1));
            asm volatile("s_waitcnt vmcnt(5)" ::: "memory");
            __builtin_amdgcn_sched_barrier(0);
            CORE(A, TIDX(i));
            LOADSET(A, TIDX(i + 2));
            asm volatile("s_waitcnt vmcnt(5)" ::: "memory");
            __builtin_amdgcn_sched_barrier(0);
            CORE(B, TIDX(i + 1));
        }
        if (i + 1 < n) {          // two tiles left
            LOADSET(B, TIDX(i + 1));
            asm volatile("s_waitcnt vmcnt(5)" ::: "memory");
            __builtin_amdgcn_sched_barrier(0);
            CORE(A, TIDX(i));
            asm volatile("s_waitcnt vmcnt(1)" ::: "memory");
            __builtin_amdgcn_sched_barrier(0);
            CORE(B, TIDX(i + 1));
        } else if (i < n) {       // one tile left
            asm volatile("s_waitcnt vmcnt(1)" ::: "memory");
            __builtin_amdgcn_sched_barrier(0);
            CORE(A, TIDX(i));
        }
    }
    if (gw < rem) {   // remainder tiles (0 for E = 2^21)
        int wt_ = n * TOTW + gw;
        floatx4 R0, R1, R2, R3;
        LOADSET(R, wt_);
        CORE(R, wt_);
    }
#undef TIDX
#undef LOADSET
#undef CORE
}

// ---------------- segment max (run-compressed atomics) ----------------
__global__ __launch_bounds__(256) void seg_max(
    const float* __restrict__ score, const int* __restrict__ batch,
    unsigned* __restrict__ segkey, int E)
{
    int t = blockIdx.x * 256 + threadIdx.x;
    int i0 = t * 8;
    if (i0 + 8 > E) return;
    int4 bA = *(const int4*)(batch + i0);
    int4 bB = *(const int4*)(batch + i0 + 4);
    floatx4 sA = *(const floatx4*)(score + i0);
    floatx4 sB = *(const floatx4*)(score + i0 + 4);
    int   ids[8] = {bA.x, bA.y, bA.z, bA.w, bB.x, bB.y, bB.z, bB.w};
    float ss[8]  = {sA[0], sA[1], sA[2], sA[3], sB[0], sB[1], sB[2], sB[3]};
    int cur = ids[0];
    float m = ss[0];
#pragma unroll
    for (int j = 1; j < 8; ++j) {
        if (ids[j] == cur) {
            m = fmaxf(m, ss[j]);
        } else {
            atomicMax(segkey + cur, fkey(m));
            cur = ids[j];
            m = ss[j];
        }
    }
    atomicMax(segkey + cur, fkey(m));
}

// ---------------- segment denom (run-compressed atomics) ----------------
__global__ __launch_bounds__(256) void seg_denom(
    const float* __restrict__ score, const int* __restrict__ batch,
    const unsigned* __restrict__ segkey, float* __restrict__ denom, int E)
{
    int t = blockIdx.x * 256 + threadIdx.x;
    int i0 = t * 8;
    if (i0 + 8 > E) return;
    int4 bA = *(const int4*)(batch + i0);
    int4 bB = *(const int4*)(batch + i0 + 4);
    floatx4 sA = *(const floatx4*)(score + i0);
    floatx4 sB = *(const floatx4*)(score + i0 + 4);
    int   ids[8] = {bA.x, bA.y, bA.z, bA.w, bB.x, bB.y, bB.z, bB.w};
    float ss[8]  = {sA[0], sA[1], sA[2], sA[3], sB[0], sB[1], sB[2], sB[3]};
    int cur = ids[0];
    float m = funkey(segkey[cur]);
    float a = __expf(ss[0] - m);
#pragma unroll
    for (int j = 1; j < 8; ++j) {
        if (ids[j] == cur) {
            a += __expf(ss[j] - m);
        } else {
            atomicAdd(denom + cur, a);
            cur = ids[j];
            m = funkey(segkey[cur]);
            a = __expf(ss[j] - m);
        }
    }
    atomicAdd(denom + cur, a);
}

// ---------------- finalize: out = exp(s-m)/(denom+eps), in place ----------------
__global__ __launch_bounds__(256) void finalize(
    float* __restrict__ score, const int* __restrict__ batch,
    const unsigned* __restrict__ segkey, const float* __restrict__ denom, int E)
{
    int t = blockIdx.x * 256 + threadIdx.x;
    int i0 = t * 8;
    if (i0 + 8 > E) return;
    int4 bA = *(const int4*)(batch + i0);
    int4 bB = *(const int4*)(batch + i0 + 4);
    floatx4 sA = *(const floatx4*)(score + i0);
    floatx4 sB = *(const floatx4*)(score + i0 + 4);
    int   ids[8] = {bA.x, bA.y, bA.z, bA.w, bB.x, bB.y, bB.z, bB.w};
    float ss[8]  = {sA[0], sA[1], sA[2], sA[3], sB[0], sB[1], sB[2], sB[3]};
    floatx4 oA, oB;
#pragma unroll
    for (int j = 0; j < 4; ++j) {
        float mj = funkey(segkey[ids[j]]);
        oA[j] = __expf(ss[j] - mj) / (denom[ids[j]] + 1e-16f);
    }
#pragma unroll
    for (int j = 0; j < 4; ++j) {
        float mj = funkey(segkey[ids[j + 4]]);
        oB[j] = __expf(ss[j + 4] - mj) / (denom[ids[j + 4]] + 1e-16f);
    }
    *(floatx4*)(score + i0)     = oA;
    *(floatx4*)(score + i0 + 4) = oB;
}

extern "C" void kernel_launch(void* const* d_in, const int* in_sizes, int n_in,
                              void* d_out, int out_size, void* d_ws, size_t ws_size,
                              hipStream_t stream) {
    const float* x   = (const float*)d_in[0];
    const float* w1  = (const float*)d_in[1];
    const float* b1  = (const float*)d_in[2];
    const float* w2  = (const float*)d_in[3];
    const float* b2  = (const float*)d_in[4];
    const int* batch = (const int*)d_in[5];
    float* out = (float*)d_out;
    const int E = in_sizes[5];

    unsigned* segkey = (unsigned*)d_ws;
    float*    denom  = (float*)((char*)d_ws + NSEG * sizeof(unsigned));

    init_seg<<<(NSEG + 255) / 256, 256, 0, stream>>>(segkey, denom);
    // scores are written into d_out (reused as scratch), finalized in place
    mlp_score<<<768, 256, 0, stream>>>(x, w1, b1, w2, b2, out, E);
    const int nthr = E / 8;
    seg_max   <<<nthr / 256, 256, 0, stream>>>(out, batch, segkey, E);
    seg_denom <<<nthr / 256, 256, 0, stream>>>(out, batch, segkey, denom, E);
    finalize  <<<nthr / 256, 256, 0, stream>>>(out, batch, segkey, denom, E);
}

// Round 12
// 192.673 us; speedup vs baseline: 2.5938x; 1.5615x over previous
//
#include <hip/hip_runtime.h>
#include <hip/hip_bf16.h>
#include <math.h>

typedef _Float16 half8  __attribute__((ext_vector_type(8)));
typedef __fp16   fp16x2 __attribute__((ext_vector_type(2)));
typedef float    floatx4 __attribute__((ext_vector_type(4)));

#define IN_CH 64
#define HID   128
#define NSEG  4096

__device__ __forceinline__ unsigned fkey(float s) {
    unsigned u = __float_as_uint(s);
    return (u & 0x80000000u) ? ~u : (u | 0x80000000u);
}
__device__ __forceinline__ float funkey(unsigned k) {
    unsigned u = (k & 0x80000000u) ? (k ^ 0x80000000u) : ~k;
    return __uint_as_float(u);
}

// ---------------- init segment scratch ----------------
__global__ void init_seg(unsigned* __restrict__ segkey, float* __restrict__ denom) {
    int i = blockIdx.x * blockDim.x + threadIdx.x;
    if (i < NSEG) { segkey[i] = 0u; denom[i] = 0.0f; }
}

// ---------------- fused MLP -> scores ----------------
// R6-verified swapped-operand MFMA core. R12: TWO independent 16-edge tile
// chains per loop iteration (disjoint regsets -> scheduler interleaves the
// MFMA/VALU chains; per-tile dependent-chain cost ~halves). Compiler-scheduled
// (no asm fences -- R11 showed pinning serializes). No LDS. grid 512,
// launch_bounds(256,2): ~245 VGPR, no spill, 8 waves/CU.
__global__ __launch_bounds__(256, 2) void mlp_score(
    const float* __restrict__ x, const float* __restrict__ w1,
    const float* __restrict__ b1, const float* __restrict__ w2,
    const float* __restrict__ b2, float* __restrict__ score, int E)
{
    const int tid  = threadIdx.x;
    const int lane = tid & 63;
    const int wid  = tid >> 6;
    const int g    = lane >> 4;   // 0..3
    const int l15  = lane & 15;   // 0..15

    // ---- one-time: w1 A-fragments (64 VGPRs), RTN cvt
    half8 afr[2][8];
#pragma unroll
    for (int ks = 0; ks < 2; ++ks)
#pragma unroll
        for (int ct = 0; ct < 8; ++ct) {
            const float* wp = w1 + (size_t)(ks * 32 + g * 8) * HID + ct * 16 + l15;
            half8 h;
#pragma unroll
            for (int j = 0; j < 8; ++j) h[j] = (_Float16)wp[(size_t)j * HID];
            afr[ks][ct] = h;
        }

    // ---- one-time: bias-as-C and w2 fragments
    floatx4 biasC[8], w2r[8];
#pragma unroll
    for (int ct = 0; ct < 8; ++ct)
#pragma unroll
        for (int r = 0; r < 4; ++r) {
            biasC[ct][r] = b1[ct * 16 + g * 4 + r];
            w2r[ct][r]   = w2[ct * 16 + g * 4 + r];
        }
    const float b2v = b2[0];

    const int nwtile = E >> 4;                  // 16-edge tiles
    const int TOTW   = (int)gridDim.x * 4;      // total waves
    const int gw     = blockIdx.x * 4 + wid;
    const int n      = nwtile / TOTW;           // tiles per wave
    const int rem    = nwtile - n * TOTW;
    const size_t laneoff = (size_t)l15 * IN_CH + g * 8;

    union H8 { half8 h8; fp16x2 h2[4]; };

#define TIDX(I) (gw + (I) * TOTW)

#define LOADSET(F, T) do {                                            \
        const float* xr = x + (size_t)(T) * (16 * IN_CH) + laneoff;   \
        F##0 = *(const floatx4*)(xr);                                 \
        F##1 = *(const floatx4*)(xr + 4);                             \
        F##2 = *(const floatx4*)(xr + 32);                            \
        F##3 = *(const floatx4*)(xr + 36);                            \
    } while (0)

#define CORE(F, WT) do {                                              \
        H8 ub, uc;                                                    \
        ub.h2[0] = __builtin_amdgcn_cvt_pkrtz(F##0[0], F##0[1]);      \
        ub.h2[1] = __builtin_amdgcn_cvt_pkrtz(F##0[2], F##0[3]);      \
        ub.h2[2] = __builtin_amdgcn_cvt_pkrtz(F##1[0], F##1[1]);      \
        ub.h2[3] = __builtin_amdgcn_cvt_pkrtz(F##1[2], F##1[3]);      \
        uc.h2[0] = __builtin_amdgcn_cvt_pkrtz(F##2[0], F##2[1]);      \
        uc.h2[1] = __builtin_amdgcn_cvt_pkrtz(F##2[2], F##2[3]);      \
        uc.h2[2] = __builtin_amdgcn_cvt_pkrtz(F##3[0], F##3[1]);      \
        uc.h2[3] = __builtin_amdgcn_cvt_pkrtz(F##3[2], F##3[3]);      \
        floatx4 acc[8];                                               \
        _Pragma("unroll")                                             \
        for (int ct = 0; ct < 8; ++ct)                                \
            acc[ct] = __builtin_amdgcn_mfma_f32_16x16x32_f16(afr[0][ct], ub.h8, biasC[ct], 0, 0, 0); \
        _Pragma("unroll")                                             \
        for (int ct = 0; ct < 8; ++ct)                                \
            acc[ct] = __builtin_amdgcn_mfma_f32_16x16x32_f16(afr[1][ct], uc.h8, acc[ct], 0, 0, 0);   \
        float s0 = 0.f, s1 = 0.f, s2 = 0.f, s3 = 0.f;                 \
        _Pragma("unroll")                                             \
        for (int ct = 0; ct < 8; ++ct) {                              \
            s0 += fmaxf(acc[ct][0], 0.f) * w2r[ct][0];                \
            s1 += fmaxf(acc[ct][1], 0.f) * w2r[ct][1];                \
            s2 += fmaxf(acc[ct][2], 0.f) * w2r[ct][2];                \
            s3 += fmaxf(acc[ct][3], 0.f) * w2r[ct][3];                \
        }                                                             \
        float s = (s0 + s1) + (s2 + s3);                              \
        s += __shfl_xor(s, 16);                                       \
        s += __shfl_xor(s, 32);                                       \
        if (lane < 16)                                                \
            score[(size_t)(WT) * 16 + l15] = s + b2v;                 \
    } while (0)

    // two independent tile chains per iteration (ILP=2)
    int i = 0;
    for (; i + 1 < n; i += 2) {
        floatx4 A0, A1, A2, A3, B0, B1, B2, B3;
        LOADSET(A, TIDX(i));
        LOADSET(B, TIDX(i + 1));
        CORE(A, TIDX(i));
        CORE(B, TIDX(i + 1));
    }
    if (i < n) {
        floatx4 A0, A1, A2, A3;
        LOADSET(A, TIDX(i));
        CORE(A, TIDX(i));
    }
    if (gw < rem) {   // remainder tiles (0 for E = 2^21)
        int wt_ = n * TOTW + gw;
        floatx4 R0, R1, R2, R3;
        LOADSET(R, wt_);
        CORE(R, wt_);
    }
#undef TIDX
#undef LOADSET
#undef CORE
}

// ---------------- segment max (run-compressed atomics) ----------------
__global__ __launch_bounds__(256) void seg_max(
    const float* __restrict__ score, const int* __restrict__ batch,
    unsigned* __restrict__ segkey, int E)
{
    int t = blockIdx.x * 256 + threadIdx.x;
    int i0 = t * 8;
    if (i0 + 8 > E) return;
    int4 bA = *(const int4*)(batch + i0);
    int4 bB = *(const int4*)(batch + i0 + 4);
    floatx4 sA = *(const floatx4*)(score + i0);
    floatx4 sB = *(const floatx4*)(score + i0 + 4);
    int   ids[8] = {bA.x, bA.y, bA.z, bA.w, bB.x, bB.y, bB.z, bB.w};
    float ss[8]  = {sA[0], sA[1], sA[2], sA[3], sB[0], sB[1], sB[2], sB[3]};
    int cur = ids[0];
    float m = ss[0];
#pragma unroll
    for (int j = 1; j < 8; ++j) {
        if (ids[j] == cur) {
            m = fmaxf(m, ss[j]);
        } else {
            atomicMax(segkey + cur, fkey(m));
            cur = ids[j];
            m = ss[j];
        }
    }
    atomicMax(segkey + cur, fkey(m));
}

// ---------------- segment denom (run-compressed atomics) ----------------
__global__ __launch_bounds__(256) void seg_denom(
    const float* __restrict__ score, const int* __restrict__ batch,
    const unsigned* __restrict__ segkey, float* __restrict__ denom, int E)
{
    int t = blockIdx.x * 256 + threadIdx.x;
    int i0 = t * 8;
    if (i0 + 8 > E) return;
    int4 bA = *(const int4*)(batch + i0);
    int4 bB = *(const int4*)(batch + i0 + 4);
    floatx4 sA = *(const floatx4*)(score + i0);
    floatx4 sB = *(const floatx4*)(score + i0 + 4);
    int   ids[8] = {bA.x, bA.y, bA.z, bA.w, bB.x, bB.y, bB.z, bB.w};
    float ss[8]  = {sA[0], sA[1], sA[2], sA[3], sB[0], sB[1], sB[2], sB[3]};
    int cur = ids[0];
    float m = funkey(segkey[cur]);
    float a = __expf(ss[0] - m);
#pragma unroll
    for (int j = 1; j < 8; ++j) {
        if (ids[j] == cur) {
            a += __expf(ss[j] - m);
        } else {
            atomicAdd(denom + cur, a);
            cur = ids[j];
            m = funkey(segkey[cur]);
            a = __expf(ss[j] - m);
        }
    }
    atomicAdd(denom + cur, a);
}

// ---------------- finalize: out = exp(s-m)/(denom+eps), in place ----------------
__global__ __launch_bounds__(256) void finalize(
    float* __restrict__ score, const int* __restrict__ batch,
    const unsigned* __restrict__ segkey, const float* __restrict__ denom, int E)
{
    int t = blockIdx.x * 256 + threadIdx.x;
    int i0 = t * 8;
    if (i0 + 8 > E) return;
    int4 bA = *(const int4*)(batch + i0);
    int4 bB = *(const int4*)(batch + i0 + 4);
    floatx4 sA = *(const floatx4*)(score + i0);
    floatx4 sB = *(const floatx4*)(score + i0 + 4);
    int   ids[8] = {bA.x, bA.y, bA.z, bA.w, bB.x, bB.y, bB.z, bB.w};
    float ss[8]  = {sA[0], sA[1], sA[2], sA[3], sB[0], sB[1], sB[2], sB[3]};
    floatx4 oA, oB;
#pragma unroll
    for (int j = 0; j < 4; ++j) {
        float mj = funkey(segkey[ids[j]]);
        oA[j] = __expf(ss[j] - mj) / (denom[ids[j]] + 1e-16f);
    }
#pragma unroll
    for (int j = 0; j < 4; ++j) {
        float mj = funkey(segkey[ids[j + 4]]);
        oB[j] = __expf(ss[j + 4] - mj) / (denom[ids[j + 4]] + 1e-16f);
    }
    *(floatx4*)(score + i0)     = oA;
    *(floatx4*)(score + i0 + 4) = oB;
}

extern "C" void kernel_launch(void* const* d_in, const int* in_sizes, int n_in,
                              void* d_out, int out_size, void* d_ws, size_t ws_size,
                              hipStream_t stream) {
    const float* x   = (const float*)d_in[0];
    const float* w1  = (const float*)d_in[1];
    const float* b1  = (const float*)d_in[2];
    const float* w2  = (const float*)d_in[3];
    const float* b2  = (const float*)d_in[4];
    const int* batch = (const int*)d_in[5];
    float* out = (float*)d_out;
    const int E = in_sizes[5];

    unsigned* segkey = (unsigned*)d_ws;
    float*    denom  = (float*)((char*)d_ws + NSEG * sizeof(unsigned));

    init_seg<<<(NSEG + 255) / 256, 256, 0, stream>>>(segkey, denom);
    // scores are written into d_out (reused as scratch), finalized in place
    mlp_score<<<512, 256, 0, stream>>>(x, w1, b1, w2, b2, out, E);
    const int nthr = E / 8;
    seg_max   <<<nthr / 256, 256, 0, stream>>>(out, batch, segkey, E);
    seg_denom <<<nthr / 256, 256, 0, stream>>>(out, batch, segkey, denom, E);
    finalize  <<<nthr / 256, 256, 0, stream>>>(out, batch, segkey, denom, E);
}